// Round 6
// baseline (37.135 us; speedup 1.0000x reference)
//
#include <hip/hip_runtime.h>

// Bidirectional Chamfer loss, fused:
//   out = 1e-4 * ( sum_n min_m |shape[b,n]-skel[b,m]|^2
//                + sum_m min_n |skel[b,m]-shape[b,n]|^2 )
//
// R6:
//  - chamfer: QPT=4 -> 2048 blocks = 8 blocks/CU = 8 waves/SIMD; inner
//    processes 2 targets per min via fminf(fminf(m,e0),e1) -> v_min3_f32
//    (3.5 VALU/pair, floor ~6 us).
//  - reduce: 640 blocks, 4 lanes per query (shfl_xor min), then clamp+sum.
//  - final fused into reduce via last-block ticket (atomicExch psum +
//    threadfence + counter; coherent atomic re-reads; deterministic).
//    Counter zeroed by chamfer block (0,0) each call.

#define CHUNK  64     // targets per block tile (1 KB in LDS)
#define QPT    4      // query points per thread
#define BIGF   3.4e38f

// ws layout (floats):
//  dir1 partials [b][ch][q] : 4 x 32 x 8192 = 1,048,576
//  dir2 partials [b][ch][q] : 4 x 128 x 2048 = 1,048,576 (at P2_OFF)
//  psum: RBLOCKS floats at PSUM_OFF; counter (uint) at PSUM_OFF + 1024.
#define P2_OFF   1048576
#define PSUM_OFF 2097152
#define RBLOCKS  640

__global__ __launch_bounds__(256) void chamfer_kernel(
    const float* __restrict__ shape,  // [4, 8192, 3]
    const float* __restrict__ skel,   // [4, 2048, 3]
    float* __restrict__ pw)           // partials + psum + counter
{
    const int b   = blockIdx.y;
    const int tid = threadIdx.x;

    // Zero the reduce ticket counter once per call (visible at kernel end).
    if (blockIdx.x == 0 && b == 0 && tid == 0)
        ((unsigned int*)pw)[PSUM_OFF + 1024] = 0u;

    // 512 tiles/batch: dir1 = 8 qb x 32 ch, dir2 = 2 qb x 128 ch.
    const float* q; const float* t; float* pbase;
    int nq, mt, qb, ch;
    int x = blockIdx.x;
    if (x < 256) {                    // dir1: shape -> skel
        q = shape; t = skel; nq = 8192; mt = 2048;
        qb = x >> 5; ch = x & 31;
        pbase = pw + ((size_t)b * 32 + ch) * 8192;
    } else {                          // dir2: skel -> shape
        x -= 256;
        q = skel; t = shape; nq = 2048; mt = 8192;
        qb = x >> 7; ch = x & 127;
        pbase = pw + P2_OFF + ((size_t)b * 128 + ch) * 2048;
    }

    __shared__ float4 lds[CHUNK];

    // Stage CHUNK targets as (x, y, z, |t|^2).
    if (tid < CHUNK) {
        const float* tb = t + ((size_t)b * mt + ch * CHUNK) * 3;
        float tx = tb[tid * 3 + 0], ty = tb[tid * 3 + 1], tz = tb[tid * 3 + 2];
        lds[tid] = make_float4(tx, ty, tz, tx * tx + ty * ty + tz * tz);
    }

    // My QPT query points: precompute -2q and |q|^2.
    const int q0 = qb * 1024 + tid;               // queries q0 + k*256
    const float* qp = q + ((size_t)b * nq + q0) * 3;
    float nqx[QPT], nqy[QPT], nqz[QPT], qsq[QPT], mn[QPT];
    #pragma unroll
    for (int k = 0; k < QPT; ++k) {
        float xq = qp[k * 768 + 0];               // 768 = 256 pts * 3
        float yq = qp[k * 768 + 1];
        float zq = qp[k * 768 + 2];
        nqx[k] = -2.0f * xq; nqy[k] = -2.0f * yq; nqz[k] = -2.0f * zq;
        qsq[k] = xq * xq + yq * yq + zq * zq;
        mn[k]  = BIGF;
    }

    __syncthreads();

    // 3.5 VALU/pair: 2 targets -> 6 FMA + 1 min3.
    #pragma unroll 4
    for (int j = 0; j < CHUNK; j += 2) {
        float4 ta = lds[j + 0];                   // broadcast: conflict-free
        float4 tb = lds[j + 1];
        #pragma unroll
        for (int k = 0; k < QPT; ++k) {
            float e0 = fmaf(nqx[k], ta.x,
                       fmaf(nqy[k], ta.y,
                       fmaf(nqz[k], ta.z, ta.w)));
            float e1 = fmaf(nqx[k], tb.x,
                       fmaf(nqy[k], tb.y,
                       fmaf(nqz[k], tb.z, tb.w)));
            mn[k] = fminf(fminf(mn[k], e0), e1);  // v_min3_f32
        }
    }

    // One coalesced store per (query, chunk) partial — no atomics.
    #pragma unroll
    for (int k = 0; k < QPT; ++k)
        pbase[q0 + k * 256] = qsq[k] + mn[k];
}

// 640 blocks: 64 queries/block, 4 lanes per query split over chunks.
// Blocks 0..511 = dir1 (32 chunks), 512..639 = dir2 (128 chunks).
// Last block (ticket) sums the 640 psum entries and writes the output.
__global__ __launch_bounds__(256) void reduce_kernel(
    float* __restrict__ pw, float* __restrict__ out)
{
    const int blk = blockIdx.x, tid = threadIdx.x;
    const int sub = tid & 3, qi = tid >> 2;       // 4 lanes per query
    float* psum = pw + PSUM_OFF;
    unsigned int* counter = (unsigned int*)pw + PSUM_OFF + 1024;

    float m = BIGF;
    if (blk < 512) {                              // dir1: 8 loads/lane
        const int b  = blk >> 7;
        const int ql = ((blk & 127) << 6) + qi;
        const float* p = pw + (size_t)b * 32 * 8192 + ql;
        #pragma unroll
        for (int i = 0; i < 8; ++i)
            m = fminf(m, p[(sub * 8 + i) * 8192]);
    } else {                                      // dir2: 32 loads/lane
        const int z  = blk - 512;
        const int b  = z >> 5;
        const int ql = ((z & 31) << 6) + qi;
        const float* p = pw + P2_OFF + (size_t)b * 128 * 2048 + ql;
        #pragma unroll
        for (int i = 0; i < 32; ++i)
            m = fminf(m, p[(sub * 32 + i) * 2048]);
    }

    // Min across the 4-lane group, clamp, keep one copy.
    m = fminf(m, __shfl_xor(m, 1));
    m = fminf(m, __shfl_xor(m, 2));
    float s = (sub == 0) ? fmaxf(m, 0.0f) : 0.0f;

    // Wave + block sum.
    #pragma unroll
    for (int off = 32; off > 0; off >>= 1)
        s += __shfl_down(s, off);

    __shared__ float wsum[4];
    __shared__ bool  sLast;
    const int lane = tid & 63, w = tid >> 6;
    if (lane == 0) wsum[w] = s;
    __syncthreads();

    if (tid == 0) {
        float tot = (wsum[0] + wsum[1]) + (wsum[2] + wsum[3]);
        atomicExch(&psum[blk], tot);              // device-coherent publish
        __threadfence();
        unsigned int t = atomicAdd(counter, 1u);
        sLast = (t == RBLOCKS - 1);
    }
    __syncthreads();

    if (sLast) {
        // Coherent re-reads (RMW +0); fixed-order tree => deterministic.
        float s2 = atomicAdd(&psum[tid], 0.0f)
                 + atomicAdd(&psum[tid + 256], 0.0f);
        if (tid < 128) s2 += atomicAdd(&psum[tid + 512], 0.0f);

        #pragma unroll
        for (int off = 32; off > 0; off >>= 1)
            s2 += __shfl_down(s2, off);
        if (lane == 0) wsum[w] = s2;
        __syncthreads();
        if (tid == 0)
            out[0] = ((wsum[0] + wsum[1]) + (wsum[2] + wsum[3])) * 1.0e-4f;
    }
}

extern "C" void kernel_launch(void* const* d_in, const int* in_sizes, int n_in,
                              void* d_out, int out_size, void* d_ws, size_t ws_size,
                              hipStream_t stream) {
    const float* shape = (const float*)d_in[0];   // [4, 8192, 3]
    const float* skel  = (const float*)d_in[1];   // [4, 2048, 3]
    float* out         = (float*)d_out;           // scalar f32
    float* pw          = (float*)d_ws;

    // 512 tiles/batch x 4 batches = 2048 blocks (8/CU, 8 waves/SIMD).
    chamfer_kernel<<<dim3(512, 4), 256, 0, stream>>>(shape, skel, pw);

    // 640 blocks; last one finalizes the scalar output.
    reduce_kernel<<<RBLOCKS, 256, 0, stream>>>(pw, out);
}

// Round 7
// 24.573 us; speedup vs baseline: 1.5112x; 1.5112x over previous
//
#include <hip/hip_runtime.h>

// Bidirectional Chamfer loss, fused:
//   out = 1e-4 * ( sum_n min_m |shape[b,n]-skel[b,m]|^2
//                + sum_m min_n |skel[b,m]-shape[b,n]|^2 )
//
// R7: revert R6's QPT=4 (doubled total LDS reads -> LDS-issue-bound,
// 31.6->37.1 regression). Keep R5 chamfer structure (QPT=8, CHUNK=64,
// 1024 blocks = 4/CU) and keep ONLY the two proven R6 pieces:
//  - min3 pairing in the inner loop (3.5 VALU/pair, floor ~6 us)
//  - 640-block reduce (4 lanes/query, coalesced), non-atomic + tiny final.

#define CHUNK  64     // targets per block tile (1 KB in LDS)
#define QPT    8      // query points per thread
#define BIGF   3.4e38f

// ws layout (floats):
//  dir1 partials [b][ch][q] : 4 x 32 x 8192 = 1,048,576
//  dir2 partials [b][ch][q] : 4 x 128 x 2048 = 1,048,576 (at P2_OFF)
//  psum: RBLOCKS floats at PSUM_OFF
#define P2_OFF   1048576
#define PSUM_OFF 2097152
#define RBLOCKS  640

__global__ __launch_bounds__(256) void chamfer_kernel(
    const float* __restrict__ shape,  // [4, 8192, 3]
    const float* __restrict__ skel,   // [4, 2048, 3]
    float* __restrict__ pw)           // partial mins
{
    const int b   = blockIdx.y;
    const int tid = threadIdx.x;

    // 256 tiles/batch: dir1 = 4 qb x 32 ch, dir2 = 1 qb x 128 ch.
    const float* q; const float* t; float* pbase;
    int nq, mt, qb, ch;
    int x = blockIdx.x;
    if (x < 128) {                    // dir1: shape -> skel
        q = shape; t = skel; nq = 8192; mt = 2048;
        qb = x >> 5; ch = x & 31;
        pbase = pw + ((size_t)b * 32 + ch) * 8192;
    } else {                          // dir2: skel -> shape
        x -= 128;
        q = skel; t = shape; nq = 2048; mt = 8192;
        qb = 0; ch = x;
        pbase = pw + P2_OFF + ((size_t)b * 128 + ch) * 2048;
    }

    __shared__ float4 lds[CHUNK];

    // Stage CHUNK targets as (x, y, z, |t|^2).
    if (tid < CHUNK) {
        const float* tb = t + ((size_t)b * mt + ch * CHUNK) * 3;
        float tx = tb[tid * 3 + 0], ty = tb[tid * 3 + 1], tz = tb[tid * 3 + 2];
        lds[tid] = make_float4(tx, ty, tz, tx * tx + ty * ty + tz * tz);
    }

    // My QPT query points: precompute -2q and |q|^2.
    const int q0 = qb * 2048 + tid;               // queries q0 + k*256
    const float* qp = q + ((size_t)b * nq + q0) * 3;
    float nqx[QPT], nqy[QPT], nqz[QPT], qsq[QPT], mn[QPT];
    #pragma unroll
    for (int k = 0; k < QPT; ++k) {
        float xq = qp[k * 768 + 0];               // 768 = 256 pts * 3
        float yq = qp[k * 768 + 1];
        float zq = qp[k * 768 + 2];
        nqx[k] = -2.0f * xq; nqy[k] = -2.0f * yq; nqz[k] = -2.0f * zq;
        qsq[k] = xq * xq + yq * yq + zq * zq;
        mn[k]  = BIGF;
    }

    __syncthreads();

    // 3.5 VALU/pair: 2 targets x 8 queries = 12 FMA + 8 (wait: 6 FMA + 1 min3 per query-pair)
    #pragma unroll 4
    for (int j = 0; j < CHUNK; j += 2) {
        float4 ta = lds[j + 0];                   // broadcast: conflict-free
        float4 tb = lds[j + 1];
        #pragma unroll
        for (int k = 0; k < QPT; ++k) {
            float e0 = fmaf(nqx[k], ta.x,
                       fmaf(nqy[k], ta.y,
                       fmaf(nqz[k], ta.z, ta.w)));
            float e1 = fmaf(nqx[k], tb.x,
                       fmaf(nqy[k], tb.y,
                       fmaf(nqz[k], tb.z, tb.w)));
            mn[k] = fminf(fminf(mn[k], e0), e1);  // v_min3_f32
        }
    }

    // One coalesced store per (query, chunk) partial — no atomics.
    #pragma unroll
    for (int k = 0; k < QPT; ++k)
        pbase[q0 + k * 256] = qsq[k] + mn[k];
}

// 640 blocks: 64 queries/block, 4 lanes per query split over chunks.
// Blocks 0..511 = dir1 (32 chunks), 512..639 = dir2 (128 chunks).
__global__ __launch_bounds__(256) void reduce_kernel(
    const float* __restrict__ pw, float* __restrict__ psum)
{
    const int blk = blockIdx.x, tid = threadIdx.x;
    const int sub = tid & 3, qi = tid >> 2;       // 4 lanes per query

    float m = BIGF;
    if (blk < 512) {                              // dir1: 8 loads/lane
        const int b  = blk >> 7;
        const int ql = ((blk & 127) << 6) + qi;
        const float* p = pw + (size_t)b * 32 * 8192 + ql;
        #pragma unroll
        for (int i = 0; i < 8; ++i)
            m = fminf(m, p[(sub * 8 + i) * 8192]);
    } else {                                      // dir2: 32 loads/lane
        const int z  = blk - 512;
        const int b  = z >> 5;
        const int ql = ((z & 31) << 6) + qi;
        const float* p = pw + P2_OFF + (size_t)b * 128 * 2048 + ql;
        #pragma unroll
        for (int i = 0; i < 32; ++i)
            m = fminf(m, p[(sub * 32 + i) * 2048]);
    }

    // Min across the 4-lane group, clamp, keep one copy.
    m = fminf(m, __shfl_xor(m, 1));
    m = fminf(m, __shfl_xor(m, 2));
    float s = (sub == 0) ? fmaxf(m, 0.0f) : 0.0f;

    // Wave + block sum.
    #pragma unroll
    for (int off = 32; off > 0; off >>= 1)
        s += __shfl_down(s, off);

    __shared__ float wsum[4];
    const int lane = tid & 63, w = tid >> 6;
    if (lane == 0) wsum[w] = s;
    __syncthreads();
    if (tid == 0) psum[blk] = (wsum[0] + wsum[1]) + (wsum[2] + wsum[3]);
}

__global__ __launch_bounds__(256) void final_kernel(
    const float* __restrict__ psum, float* __restrict__ out)
{
    float s = psum[threadIdx.x] + psum[threadIdx.x + 256];
    if (threadIdx.x < 128) s += psum[threadIdx.x + 512];

    #pragma unroll
    for (int off = 32; off > 0; off >>= 1)
        s += __shfl_down(s, off);

    __shared__ float wsum[4];
    const int lane = threadIdx.x & 63, w = threadIdx.x >> 6;
    if (lane == 0) wsum[w] = s;
    __syncthreads();
    if (threadIdx.x == 0)
        out[0] = ((wsum[0] + wsum[1]) + (wsum[2] + wsum[3])) * 1.0e-4f;
}

extern "C" void kernel_launch(void* const* d_in, const int* in_sizes, int n_in,
                              void* d_out, int out_size, void* d_ws, size_t ws_size,
                              hipStream_t stream) {
    const float* shape = (const float*)d_in[0];   // [4, 8192, 3]
    const float* skel  = (const float*)d_in[1];   // [4, 2048, 3]
    float* out         = (float*)d_out;           // scalar f32
    float* pw          = (float*)d_ws;

    // 256 tiles/batch x 4 batches = 1024 blocks (4/CU, 4 waves/SIMD).
    chamfer_kernel<<<dim3(256, 4), 256, 0, stream>>>(shape, skel, pw);

    // 640 blocks, then tiny deterministic final sum.
    reduce_kernel<<<RBLOCKS, 256, 0, stream>>>(pw, pw + PSUM_OFF);
    final_kernel<<<1, 256, 0, stream>>>(pw + PSUM_OFF, out);
}